// Round 4
// baseline (3745.130 us; speedup 1.0000x reference)
//
#include <hip/hip_runtime.h>

// features: (16, 64, 65536) f32, coords: (16, 3, 65536) f32, resolution = 32
constexpr int Rr = 32;
constexpr int R2 = Rr * Rr;          // 1024
constexpr int R3 = Rr * Rr * Rr;     // 32768
constexpr int Bb = 16;
constexpr int Cc = 64;
constexpr int Nn = 65536;
constexpr int VOX_ELEMS = Bb * Cc * R3;    // 33,554,432
constexpr int NCELL  = Bb * R3;            // 524,288
constexpr int NSLOTS = Bb * Nn;            // 1,048,576

// ---------------- Kernel A: norm_coords + voxel idx + int counts ----------------
__global__ __launch_bounds__(256) void vox_coords_kernel(
    const float* __restrict__ coords,
    float* __restrict__ norm_out,
    int* __restrict__ idx_out,
    int* __restrict__ cnt)
{
    int t = blockIdx.x * 256 + threadIdx.x;        // t = b*N + i
    int b = t >> 16;
    int i = t & (Nn - 1);

    const float* cp = coords + (size_t)b * 3 * Nn + i;
    float x = cp[0];
    float y = cp[Nn];
    float z = cp[2 * Nn];

    float nx = fminf(fmaxf((x + 1.0f) * 16.0f, 0.0f), 31.0f);
    float ny = fminf(fmaxf((y + 1.0f) * 16.0f, 0.0f), 31.0f);
    float nz = fminf(fmaxf((z + 1.0f) * 16.0f, 0.0f), 31.0f);

    float* np_ = norm_out + (size_t)b * 3 * Nn + i;
    np_[0]      = nx;
    np_[Nn]     = ny;
    np_[2 * Nn] = nz;

    int idx = (int)rintf(nx) * R2 + (int)rintf(ny) * Rr + (int)rintf(nz);

    idx_out[t] = idx;
    atomicAdd(&cnt[(b << 15) + idx], 1);
}

// ---------------- Scan phase 1 ----------------
__global__ __launch_bounds__(256) void scan1_kernel(
    const int* __restrict__ cnt, int* __restrict__ cursor, int* __restrict__ bsums)
{
    __shared__ int sm[256];
    int t = blockIdx.x * 256 + threadIdx.x;
    int v = cnt[t];
    sm[threadIdx.x] = v;
    __syncthreads();
#pragma unroll
    for (int off = 1; off < 256; off <<= 1) {
        int x = (threadIdx.x >= off) ? sm[threadIdx.x - off] : 0;
        __syncthreads();
        sm[threadIdx.x] += x;
        __syncthreads();
    }
    cursor[t] = sm[threadIdx.x] - v;
    if (threadIdx.x == 255) bsums[blockIdx.x] = sm[255];
}

// ---------------- Scan phase 2 ----------------
__global__ __launch_bounds__(256) void scan2_kernel(int* __restrict__ bsums)
{
    __shared__ int sm[256];
    int carry = 0;
    for (int chunk = 0; chunk < 2048; chunk += 256) {
        int v = bsums[chunk + threadIdx.x];
        sm[threadIdx.x] = v;
        __syncthreads();
#pragma unroll
        for (int off = 1; off < 256; off <<= 1) {
            int x = (threadIdx.x >= off) ? sm[threadIdx.x - off] : 0;
            __syncthreads();
            sm[threadIdx.x] += x;
            __syncthreads();
        }
        bsums[chunk + threadIdx.x] = carry + sm[threadIdx.x] - v;
        carry += sm[255];
        __syncthreads();
    }
}

// ---------------- Scan phase 3 ----------------
__global__ __launch_bounds__(256) void scan3_kernel(
    int* __restrict__ cursor, const int* __restrict__ bsums)
{
    int t = blockIdx.x * 256 + threadIdx.x;
    cursor[t] += bsums[blockIdx.x];
}

// ---------------- Binning: deposit (cell<<16 | pid) in sorted order ----------------
__global__ __launch_bounds__(256) void bin_kernel(
    const int* __restrict__ idx_ws, int* __restrict__ cursor, int* __restrict__ packed)
{
    int t = blockIdx.x * 256 + threadIdx.x;
    int b = t >> 16;
    int i = t & (Nn - 1);
    int idx = idx_ws[t];
    int slot = atomicAdd(&cursor[(b << 15) + idx], 1);   // L2-resident 2 MB table
    packed[slot] = (idx << 16) | i;                      // 15b cell | 16b pid
}
// after this, cursor[cell] == END offset of the cell's slot segment

// ---------------- Transpose: feat (b,c,n) -> featT (b_local, n, c) ----------------
__global__ __launch_bounds__(256) void transpose_kernel(
    const float* __restrict__ feat, float* __restrict__ featT, int b0)
{
    __shared__ float lds[64 * 65];                 // [n][c], stride 65
    int bb   = blockIdx.x >> 10;                   // chunk-local b
    int tile = blockIdx.x & 1023;
    int b    = b0 + bb;
    int n0   = tile << 6;
    int t    = threadIdx.x;

#pragma unroll
    for (int k = 0; k < 4; ++k) {
        int c  = (t >> 4) + (k << 4);
        int n4 = (t & 15) << 2;
        float4 v = *(const float4*)(feat + (((size_t)(b * Cc + c)) << 16) + n0 + n4);
        lds[(n4 + 0) * 65 + c] = v.x;
        lds[(n4 + 1) * 65 + c] = v.y;
        lds[(n4 + 2) * 65 + c] = v.z;
        lds[(n4 + 3) * 65 + c] = v.w;
    }
    __syncthreads();
#pragma unroll
    for (int k = 0; k < 4; ++k) {
        int n  = (t >> 4) + (k << 4);
        int c4 = (t & 15) << 2;
        float4 w;
        w.x = lds[n * 65 + c4 + 0];
        w.y = lds[n * 65 + c4 + 1];
        w.z = lds[n * 65 + c4 + 2];
        w.w = lds[n * 65 + c4 + 3];
        *(float4*)(featT + (((size_t)(bb << 16) + n0 + n) << 6) + c4) = w;
    }
}

// ---------------- Gather: 64 voxels x 64 channels, 8-wide pipelined ----------------
__global__ __launch_bounds__(256) void gather_kernel(
    const float* __restrict__ featT,
    const int* __restrict__ cursor,   // end offsets per cell
    const int* __restrict__ cnt,
    const int* __restrict__ packed,
    float* __restrict__ vox, int b0)
{
    __shared__ float sm[64 * 65];                  // [vloc][c], stride 65
    int bb   = blockIdx.x >> 9;                    // chunk-local b
    int vgrp = blockIdx.x & 511;
    int b    = b0 + bb;
    int v0   = vgrp << 6;
    int t    = threadIdx.x;
    int wave = t >> 6;
    int lane = t & 63;

    for (int i = t; i < 64 * 65; i += 256) sm[i] = 0.0f;

    int cell0 = (b << 15) + v0;
    int start = cursor[cell0] - cnt[cell0];
    int end   = cursor[cell0 + 63];
    __syncthreads();

    const float* fbase = featT + ((size_t)bb << 22);   // bb * 65536 * 64

    // 8 slots per wave per iteration, 32 per block-iteration, 2-stage pipeline.
    int s = start + wave * 8;
    int4 pa = *(const int4*)(packed + s);              // broadcast (pad-safe)
    int4 pb = *(const int4*)(packed + s + 4);
    float g0 = fbase[((size_t)(pa.x & 0xFFFF) << 6) + lane];
    float g1 = fbase[((size_t)(pa.y & 0xFFFF) << 6) + lane];
    float g2 = fbase[((size_t)(pa.z & 0xFFFF) << 6) + lane];
    float g3 = fbase[((size_t)(pa.w & 0xFFFF) << 6) + lane];
    float g4 = fbase[((size_t)(pb.x & 0xFFFF) << 6) + lane];
    float g5 = fbase[((size_t)(pb.y & 0xFFFF) << 6) + lane];
    float g6 = fbase[((size_t)(pb.z & 0xFFFF) << 6) + lane];
    float g7 = fbase[((size_t)(pb.w & 0xFFFF) << 6) + lane];

    while (s < end) {
        int ns = s + 32;
        int4 na  = *(const int4*)(packed + ns);        // prefetch next group
        int4 nb_ = *(const int4*)(packed + ns + 4);
        float h0 = fbase[((size_t)(na.x  & 0xFFFF) << 6) + lane];
        float h1 = fbase[((size_t)(na.y  & 0xFFFF) << 6) + lane];
        float h2 = fbase[((size_t)(na.z  & 0xFFFF) << 6) + lane];
        float h3 = fbase[((size_t)(na.w  & 0xFFFF) << 6) + lane];
        float h4 = fbase[((size_t)(nb_.x & 0xFFFF) << 6) + lane];
        float h5 = fbase[((size_t)(nb_.y & 0xFFFF) << 6) + lane];
        float h6 = fbase[((size_t)(nb_.z & 0xFFFF) << 6) + lane];
        float h7 = fbase[((size_t)(nb_.w & 0xFFFF) << 6) + lane];

        if (s + 0 < end) atomicAdd(&sm[((pa.x >> 16) - v0) * 65 + lane], g0);
        if (s + 1 < end) atomicAdd(&sm[((pa.y >> 16) - v0) * 65 + lane], g1);
        if (s + 2 < end) atomicAdd(&sm[((pa.z >> 16) - v0) * 65 + lane], g2);
        if (s + 3 < end) atomicAdd(&sm[((pa.w >> 16) - v0) * 65 + lane], g3);
        if (s + 4 < end) atomicAdd(&sm[((pb.x >> 16) - v0) * 65 + lane], g4);
        if (s + 5 < end) atomicAdd(&sm[((pb.y >> 16) - v0) * 65 + lane], g5);
        if (s + 6 < end) atomicAdd(&sm[((pb.z >> 16) - v0) * 65 + lane], g6);
        if (s + 7 < end) atomicAdd(&sm[((pb.w >> 16) - v0) * 65 + lane], g7);

        s = ns;
        pa = na; pb = nb_;
        g0 = h0; g1 = h1; g2 = h2; g3 = h3;
        g4 = h4; g5 = h5; g6 = h6; g7 = h7;
    }
    __syncthreads();

    // write out: vox[b][c][v0+lane] = sm / count
    int   kc  = cnt[cell0 + lane];
    float inv = kc ? 1.0f / (float)kc : 0.0f;      // empty voxel -> 0 (== 0/1e-5)
#pragma unroll
    for (int k = 0; k < 16; ++k) {
        int c = (wave << 4) + k;
        vox[(((size_t)(b * Cc + c)) << 15) + v0 + lane] = sm[lane * 65 + c] * inv;
    }
}

extern "C" void kernel_launch(void* const* d_in, const int* in_sizes, int n_in,
                              void* d_out, int out_size, void* d_ws, size_t ws_size,
                              hipStream_t stream)
{
    const float* features = (const float*)d_in[0];
    const float* coords   = (const float*)d_in[1];

    float* out      = (float*)d_out;
    float* vox      = out;
    float* norm_out = out + VOX_ELEMS;

    // ws layout: cnt | cursor | packed(+64 pad) | bsums | idx | featT(chunked)
    char* ws = (char*)d_ws;
    int* cnt    = (int*)ws;  ws += (size_t)NCELL * 4;
    int* cursor = (int*)ws;  ws += (size_t)NCELL * 4;
    int* packed = (int*)ws;  ws += (size_t)(NSLOTS + 64) * 4;
    int* bsums  = (int*)ws;  ws += 2048 * 4;
    int* idx_ws = (int*)ws;  ws += (size_t)NSLOTS * 4;
    float* featT = (float*)ws;

    size_t fixed = (size_t)(2 * NCELL + NSLOTS + 64 + 2048 + NSLOTS) * 4;
    size_t perB  = (size_t)Nn * Cc * 4;            // 16.78 MB
    int CB = (ws_size > fixed) ? (int)((ws_size - fixed) / perB) : 1;
    if (CB < 1) CB = 1;
    if (CB > 4) CB = 4;                            // keep featT chunk L3-resident

    hipMemsetAsync(cnt, 0, (size_t)NCELL * sizeof(int), stream);

    vox_coords_kernel<<<(Bb * Nn) / 256, 256, 0, stream>>>(coords, norm_out, idx_ws, cnt);
    scan1_kernel<<<NCELL / 256, 256, 0, stream>>>(cnt, cursor, bsums);
    scan2_kernel<<<1, 256, 0, stream>>>(bsums);
    scan3_kernel<<<NCELL / 256, 256, 0, stream>>>(cursor, bsums);
    bin_kernel<<<(Bb * Nn) / 256, 256, 0, stream>>>(idx_ws, cursor, packed);

    for (int b0 = 0; b0 < Bb; b0 += CB) {
        int nb = (b0 + CB <= Bb) ? CB : (Bb - b0);
        transpose_kernel<<<nb * 1024, 256, 0, stream>>>(features, featT, b0);
        gather_kernel<<<nb * 512, 256, 0, stream>>>(featT, cursor, cnt, packed, vox, b0);
    }
}

// Round 5
// 1502.943 us; speedup vs baseline: 2.4919x; 2.4919x over previous
//
#include <hip/hip_runtime.h>

// features: (16, 64, 65536) f32, coords: (16, 3, 65536) f32, resolution = 32
constexpr int Rr = 32;
constexpr int R2 = Rr * Rr;          // 1024
constexpr int R3 = Rr * Rr * Rr;     // 32768
constexpr int Bb = 16;
constexpr int Cc = 64;
constexpr int Nn = 65536;
constexpr int VOX_ELEMS = Bb * Cc * R3;    // 33,554,432
constexpr int NCELL  = Bb * R3;            // 524,288
constexpr int NSLOTS = Bb * Nn;            // 1,048,576

// ---------------- Kernel A: norm_coords + voxel idx + int counts ----------------
__global__ __launch_bounds__(256) void vox_coords_kernel(
    const float* __restrict__ coords,
    float* __restrict__ norm_out,
    int* __restrict__ idx_out,
    int* __restrict__ cnt)
{
    int t = blockIdx.x * 256 + threadIdx.x;        // t = b*N + i
    int b = t >> 16;
    int i = t & (Nn - 1);

    const float* cp = coords + (size_t)b * 3 * Nn + i;
    float x = cp[0];
    float y = cp[Nn];
    float z = cp[2 * Nn];

    float nx = fminf(fmaxf((x + 1.0f) * 16.0f, 0.0f), 31.0f);
    float ny = fminf(fmaxf((y + 1.0f) * 16.0f, 0.0f), 31.0f);
    float nz = fminf(fmaxf((z + 1.0f) * 16.0f, 0.0f), 31.0f);

    float* np_ = norm_out + (size_t)b * 3 * Nn + i;
    np_[0]      = nx;
    np_[Nn]     = ny;
    np_[2 * Nn] = nz;

    int idx = (int)rintf(nx) * R2 + (int)rintf(ny) * Rr + (int)rintf(nz);

    idx_out[t] = idx;
    atomicAdd(&cnt[(b << 15) + idx], 1);
}

// ---------------- Scan phase 1 ----------------
__global__ __launch_bounds__(256) void scan1_kernel(
    const int* __restrict__ cnt, int* __restrict__ cursor, int* __restrict__ bsums)
{
    __shared__ int sm[256];
    int t = blockIdx.x * 256 + threadIdx.x;
    int v = cnt[t];
    sm[threadIdx.x] = v;
    __syncthreads();
#pragma unroll
    for (int off = 1; off < 256; off <<= 1) {
        int x = (threadIdx.x >= off) ? sm[threadIdx.x - off] : 0;
        __syncthreads();
        sm[threadIdx.x] += x;
        __syncthreads();
    }
    cursor[t] = sm[threadIdx.x] - v;
    if (threadIdx.x == 255) bsums[blockIdx.x] = sm[255];
}

// ---------------- Scan phase 2 ----------------
__global__ __launch_bounds__(256) void scan2_kernel(int* __restrict__ bsums)
{
    __shared__ int sm[256];
    int carry = 0;
    for (int chunk = 0; chunk < 2048; chunk += 256) {
        int v = bsums[chunk + threadIdx.x];
        sm[threadIdx.x] = v;
        __syncthreads();
#pragma unroll
        for (int off = 1; off < 256; off <<= 1) {
            int x = (threadIdx.x >= off) ? sm[threadIdx.x - off] : 0;
            __syncthreads();
            sm[threadIdx.x] += x;
            __syncthreads();
        }
        bsums[chunk + threadIdx.x] = carry + sm[threadIdx.x] - v;
        carry += sm[255];
        __syncthreads();
    }
}

// ---------------- Scan phase 3 ----------------
__global__ __launch_bounds__(256) void scan3_kernel(
    int* __restrict__ cursor, const int* __restrict__ bsums)
{
    int t = blockIdx.x * 256 + threadIdx.x;
    cursor[t] += bsums[blockIdx.x];
}

// ---------------- Binning: deposit (cell<<16 | pid) in sorted order ----------------
__global__ __launch_bounds__(256) void bin_kernel(
    const int* __restrict__ idx_ws, int* __restrict__ cursor, int* __restrict__ packed)
{
    int t = blockIdx.x * 256 + threadIdx.x;
    int b = t >> 16;
    int i = t & (Nn - 1);
    int idx = idx_ws[t];
    int slot = atomicAdd(&cursor[(b << 15) + idx], 1);   // L2-resident 2 MB table
    packed[slot] = (idx << 16) | i;                      // 15b cell | 16b pid
}
// after this, cursor[cell] == END offset of the cell's slot segment

// ---------------- Transpose: feat (b,c,n) -> featT (b, n, c) ----------------
__global__ __launch_bounds__(256) void transpose_kernel(
    const float* __restrict__ feat, float* __restrict__ featT)
{
    __shared__ float lds[64 * 65];                 // [n][c], stride 65
    int b    = blockIdx.x >> 10;
    int tile = blockIdx.x & 1023;
    int n0   = tile << 6;
    int t    = threadIdx.x;

#pragma unroll
    for (int k = 0; k < 4; ++k) {
        int c  = (t >> 4) + (k << 4);
        int n4 = (t & 15) << 2;
        float4 v = *(const float4*)(feat + (((size_t)(b * Cc + c)) << 16) + n0 + n4);
        lds[(n4 + 0) * 65 + c] = v.x;
        lds[(n4 + 1) * 65 + c] = v.y;
        lds[(n4 + 2) * 65 + c] = v.z;
        lds[(n4 + 3) * 65 + c] = v.w;
    }
    __syncthreads();
#pragma unroll
    for (int k = 0; k < 4; ++k) {
        int n  = (t >> 4) + (k << 4);
        int c4 = (t & 15) << 2;
        float4 w;
        w.x = lds[n * 65 + c4 + 0];
        w.y = lds[n * 65 + c4 + 1];
        w.z = lds[n * 65 + c4 + 2];
        w.w = lds[n * 65 + c4 + 3];
        *(float4*)(featT + (((size_t)(b << 16) + n0 + n) << 6) + c4) = w;
    }
}

// ---------------- Gather: 64 voxels x 64 channels, 8 waves, 8-deep branchless ----------------
__global__ __launch_bounds__(512) void gather_kernel(
    const float* __restrict__ featT,
    const int* __restrict__ cursor,   // end offsets per cell
    const int* __restrict__ cnt,
    const int* __restrict__ packed,
    float* __restrict__ vox)
{
    __shared__ float sm[65 * 65];                  // rows 0..63 = vloc, row 64 = trash
    int b    = blockIdx.x >> 9;
    int vgrp = blockIdx.x & 511;
    int v0   = vgrp << 6;
    int t    = threadIdx.x;
    int wave = t >> 6;                             // 0..7
    int lane = t & 63;

    for (int i = t; i < 65 * 65; i += 512) sm[i] = 0.0f;

    int cell0 = (b << 15) + v0;
    int start = cursor[cell0] - cnt[cell0];
    int end   = cursor[cell0 + 63];
    __syncthreads();

    const float* fbase = featT + ((size_t)b << 22);   // b * 65536 * 64

    // 8 slots per wave per iteration, 64 per block-iteration, 2-stage rotating
    // pipeline. Body is branchless: out-of-range slots are dumped in trash row 64.
    int s = start + wave * 8;
    int p0 = packed[s + 0], p1 = packed[s + 1], p2 = packed[s + 2], p3 = packed[s + 3];
    int p4 = packed[s + 4], p5 = packed[s + 5], p6 = packed[s + 6], p7 = packed[s + 7];
    float g0 = fbase[((size_t)(p0 & 0xFFFF) << 6) + lane];
    float g1 = fbase[((size_t)(p1 & 0xFFFF) << 6) + lane];
    float g2 = fbase[((size_t)(p2 & 0xFFFF) << 6) + lane];
    float g3 = fbase[((size_t)(p3 & 0xFFFF) << 6) + lane];
    float g4 = fbase[((size_t)(p4 & 0xFFFF) << 6) + lane];
    float g5 = fbase[((size_t)(p5 & 0xFFFF) << 6) + lane];
    float g6 = fbase[((size_t)(p6 & 0xFFFF) << 6) + lane];
    float g7 = fbase[((size_t)(p7 & 0xFFFF) << 6) + lane];

    while (s < end) {
        int ns = s + 64;
        int q0 = packed[ns + 0], q1 = packed[ns + 1], q2 = packed[ns + 2], q3 = packed[ns + 3];
        int q4 = packed[ns + 4], q5 = packed[ns + 5], q6 = packed[ns + 6], q7 = packed[ns + 7];
        float h0 = fbase[((size_t)(q0 & 0xFFFF) << 6) + lane];
        float h1 = fbase[((size_t)(q1 & 0xFFFF) << 6) + lane];
        float h2 = fbase[((size_t)(q2 & 0xFFFF) << 6) + lane];
        float h3 = fbase[((size_t)(q3 & 0xFFFF) << 6) + lane];
        float h4 = fbase[((size_t)(q4 & 0xFFFF) << 6) + lane];
        float h5 = fbase[((size_t)(q5 & 0xFFFF) << 6) + lane];
        float h6 = fbase[((size_t)(q6 & 0xFFFF) << 6) + lane];
        float h7 = fbase[((size_t)(q7 & 0xFFFF) << 6) + lane];

        // branchless clamped rows (trash row 64 for out-of-range slots)
        int r0 = (s + 0 < end) ? ((p0 >> 16) - v0) : 64;
        int r1 = (s + 1 < end) ? ((p1 >> 16) - v0) : 64;
        int r2 = (s + 2 < end) ? ((p2 >> 16) - v0) : 64;
        int r3 = (s + 3 < end) ? ((p3 >> 16) - v0) : 64;
        int r4 = (s + 4 < end) ? ((p4 >> 16) - v0) : 64;
        int r5 = (s + 5 < end) ? ((p5 >> 16) - v0) : 64;
        int r6 = (s + 6 < end) ? ((p6 >> 16) - v0) : 64;
        int r7 = (s + 7 < end) ? ((p7 >> 16) - v0) : 64;
        atomicAdd(&sm[r0 * 65 + lane], g0);
        atomicAdd(&sm[r1 * 65 + lane], g1);
        atomicAdd(&sm[r2 * 65 + lane], g2);
        atomicAdd(&sm[r3 * 65 + lane], g3);
        atomicAdd(&sm[r4 * 65 + lane], g4);
        atomicAdd(&sm[r5 * 65 + lane], g5);
        atomicAdd(&sm[r6 * 65 + lane], g6);
        atomicAdd(&sm[r7 * 65 + lane], g7);

        s = ns;
        p0 = q0; p1 = q1; p2 = q2; p3 = q3; p4 = q4; p5 = q5; p6 = q6; p7 = q7;
        g0 = h0; g1 = h1; g2 = h2; g3 = h3; g4 = h4; g5 = h5; g6 = h6; g7 = h7;
    }
    __syncthreads();

    // write out: vox[b][c][v0+lane] = sm[lane][c] / count[lane]
    int   kc  = cnt[cell0 + lane];
    float inv = kc ? 1.0f / (float)kc : 0.0f;      // empty voxel -> 0 (== 0/1e-5)
#pragma unroll
    for (int k = 0; k < 8; ++k) {
        int c = (wave << 3) + k;
        vox[(((size_t)(b * Cc + c)) << 15) + v0 + lane] = sm[lane * 65 + c] * inv;
    }
}

extern "C" void kernel_launch(void* const* d_in, const int* in_sizes, int n_in,
                              void* d_out, int out_size, void* d_ws, size_t ws_size,
                              hipStream_t stream)
{
    const float* features = (const float*)d_in[0];
    const float* coords   = (const float*)d_in[1];

    float* out      = (float*)d_out;
    float* vox      = out;
    float* norm_out = out + VOX_ELEMS;

    // ws layout: cnt | cursor | packed(+128 pad) | bsums | idx | featT (full 268 MB)
    char* ws = (char*)d_ws;
    int* cnt    = (int*)ws;  ws += (size_t)NCELL * 4;
    int* cursor = (int*)ws;  ws += (size_t)NCELL * 4;
    int* packed = (int*)ws;  ws += (size_t)(NSLOTS + 128) * 4;
    int* bsums  = (int*)ws;  ws += 2048 * 4;
    int* idx_ws = (int*)ws;  ws += (size_t)NSLOTS * 4;
    float* featT = (float*)ws;

    hipMemsetAsync(cnt, 0, (size_t)NCELL * sizeof(int), stream);

    vox_coords_kernel<<<(Bb * Nn) / 256, 256, 0, stream>>>(coords, norm_out, idx_ws, cnt);
    scan1_kernel<<<NCELL / 256, 256, 0, stream>>>(cnt, cursor, bsums);
    scan2_kernel<<<1, 256, 0, stream>>>(bsums);
    scan3_kernel<<<NCELL / 256, 256, 0, stream>>>(cursor, bsums);
    bin_kernel<<<(Bb * Nn) / 256, 256, 0, stream>>>(idx_ws, cursor, packed);

    transpose_kernel<<<Bb * 1024, 256, 0, stream>>>(features, featT);
    gather_kernel<<<Bb * 512, 512, 0, stream>>>(featT, cursor, cnt, packed, vox);
}

// Round 6
// 683.012 us; speedup vs baseline: 5.4833x; 2.2005x over previous
//
#include <hip/hip_runtime.h>

// features: (16, 64, 65536) f32, coords: (16, 3, 65536) f32, resolution = 32
constexpr int Rr = 32;
constexpr int R2 = Rr * Rr;          // 1024
constexpr int R3 = Rr * Rr * Rr;     // 32768
constexpr int Bb = 16;
constexpr int Cc = 64;
constexpr int Nn = 65536;
constexpr int VOX_ELEMS = Bb * Cc * R3;    // 33,554,432
constexpr int NCELL  = Bb * R3;            // 524,288
constexpr int NSLOTS = Bb * Nn;            // 1,048,576

// ---------------- Kernel A: norm_coords + voxel idx + int counts ----------------
__global__ __launch_bounds__(256) void vox_coords_kernel(
    const float* __restrict__ coords,
    float* __restrict__ norm_out,
    int* __restrict__ idx_out,
    int* __restrict__ cnt)
{
    int t = blockIdx.x * 256 + threadIdx.x;        // t = b*N + i
    int b = t >> 16;
    int i = t & (Nn - 1);

    const float* cp = coords + (size_t)b * 3 * Nn + i;
    float x = cp[0];
    float y = cp[Nn];
    float z = cp[2 * Nn];

    float nx = fminf(fmaxf((x + 1.0f) * 16.0f, 0.0f), 31.0f);
    float ny = fminf(fmaxf((y + 1.0f) * 16.0f, 0.0f), 31.0f);
    float nz = fminf(fmaxf((z + 1.0f) * 16.0f, 0.0f), 31.0f);

    float* np_ = norm_out + (size_t)b * 3 * Nn + i;
    np_[0]      = nx;
    np_[Nn]     = ny;
    np_[2 * Nn] = nz;

    int idx = (int)rintf(nx) * R2 + (int)rintf(ny) * Rr + (int)rintf(nz);

    idx_out[t] = idx;
    atomicAdd(&cnt[(b << 15) + idx], 1);
}

// ---------------- Scan phase 1 ----------------
__global__ __launch_bounds__(256) void scan1_kernel(
    const int* __restrict__ cnt, int* __restrict__ cursor, int* __restrict__ bsums)
{
    __shared__ int sm[256];
    int t = blockIdx.x * 256 + threadIdx.x;
    int v = cnt[t];
    sm[threadIdx.x] = v;
    __syncthreads();
#pragma unroll
    for (int off = 1; off < 256; off <<= 1) {
        int x = (threadIdx.x >= off) ? sm[threadIdx.x - off] : 0;
        __syncthreads();
        sm[threadIdx.x] += x;
        __syncthreads();
    }
    cursor[t] = sm[threadIdx.x] - v;
    if (threadIdx.x == 255) bsums[blockIdx.x] = sm[255];
}

// ---------------- Scan phase 2 ----------------
__global__ __launch_bounds__(256) void scan2_kernel(int* __restrict__ bsums)
{
    __shared__ int sm[256];
    int carry = 0;
    for (int chunk = 0; chunk < 2048; chunk += 256) {
        int v = bsums[chunk + threadIdx.x];
        sm[threadIdx.x] = v;
        __syncthreads();
#pragma unroll
        for (int off = 1; off < 256; off <<= 1) {
            int x = (threadIdx.x >= off) ? sm[threadIdx.x - off] : 0;
            __syncthreads();
            sm[threadIdx.x] += x;
            __syncthreads();
        }
        bsums[chunk + threadIdx.x] = carry + sm[threadIdx.x] - v;
        carry += sm[255];
        __syncthreads();
    }
}

// ---------------- Scan phase 3 ----------------
__global__ __launch_bounds__(256) void scan3_kernel(
    int* __restrict__ cursor, const int* __restrict__ bsums)
{
    int t = blockIdx.x * 256 + threadIdx.x;
    cursor[t] += bsums[blockIdx.x];
}

// ---------------- Binning: slotbuf[t] holds idx on entry, slot on exit ----------------
__global__ __launch_bounds__(256) void bin_kernel(
    int* __restrict__ slotbuf, int* __restrict__ cursor, int* __restrict__ packed)
{
    int t = blockIdx.x * 256 + threadIdx.x;
    int b = t >> 16;
    int i = t & (Nn - 1);
    int idx = slotbuf[t];                                // read idx
    int slot = atomicAdd(&cursor[(b << 15) + idx], 1);   // L2-resident 2 MB table
    packed[slot] = (idx << 16) | i;                      // 15b cell | 16b pid
    slotbuf[t] = slot;                                   // overwrite with slot
}
// after this, cursor[cell] == END offset of the cell's slot segment

// ---------------- Transpose + scatter: feat (b,c,n) -> featS[slot][c] ----------------
__global__ __launch_bounds__(256) void tscatter_kernel(
    const float* __restrict__ feat, const int* __restrict__ slotbuf,
    float* __restrict__ featS)
{
    __shared__ float lds[64 * 65];                 // [n][c], stride 65
    __shared__ int   slot_sm[64];
    int b    = blockIdx.x >> 10;
    int tile = blockIdx.x & 1023;
    int n0   = tile << 6;
    int t    = threadIdx.x;

    if (t < 64) slot_sm[t] = slotbuf[(b << 16) + n0 + t];

#pragma unroll
    for (int k = 0; k < 4; ++k) {
        int c  = (t >> 4) + (k << 4);
        int n4 = (t & 15) << 2;
        float4 v = *(const float4*)(feat + (((size_t)(b * Cc + c)) << 16) + n0 + n4);
        lds[(n4 + 0) * 65 + c] = v.x;
        lds[(n4 + 1) * 65 + c] = v.y;
        lds[(n4 + 2) * 65 + c] = v.z;
        lds[(n4 + 3) * 65 + c] = v.w;
    }
    __syncthreads();

    // each wave writes 16 point-rows: 64 lanes x 4B = one 256 B segment per store
    int wave = t >> 6, lane = t & 63;
#pragma unroll
    for (int k = 0; k < 16; ++k) {
        int n = (wave << 4) + k;
        float v = lds[n * 65 + lane];
        featS[((size_t)slot_sm[n] << 6) + lane] = v;   // random but aligned 256 B row
    }
}

// ---------------- Accumulate: contiguous slot range per 64-cell group ----------------
__global__ __launch_bounds__(512) void accum_kernel(
    const float* __restrict__ featS,
    const int* __restrict__ cursor,   // end offsets per cell
    const int* __restrict__ cnt,
    const int* __restrict__ packed,
    float* __restrict__ vox)
{
    __shared__ float sm[65 * 65];                  // rows 0..63 = cells, row 64 = trash
    int bid = blockIdx.x;
    int vg  = bid >> 4;                            // 0..511 (remapped below)
    int b   = bid & 15;

    // heavy-first remap: clip-faces ix=0,31 first, then inward; same for iy pairs
    int krank = vg >> 4;                           // 0..31 -> ix
    int prank = vg & 15;                           // 0..15 -> iy pair
    int ix = (krank & 1) ? (31 - (krank >> 1)) : (krank >> 1);
    int py = (prank & 1) ? (15 - (prank >> 1)) : (prank >> 1);
    int cell0loc = (ix << 10) + (py << 6);         // cell0 within batch, multiple of 64
    int cell0 = (b << 15) + cell0loc;

    int t = threadIdx.x, wave = t >> 6, lane = t & 63;
    for (int i = t; i < 65 * 65; i += 512) sm[i] = 0.0f;

    int start = cursor[cell0] - cnt[cell0];
    int end   = cursor[cell0 + 63];
    __syncthreads();

    // all addresses affine in s: loads pipeline freely; only the LDS row is indirect
    for (int s = start + wave * 8; s < end; s += 64) {
#pragma unroll
        for (int j = 0; j < 8; ++j) {
            int   pk = packed[s + j];                        // sequential 4B
            float f  = featS[((size_t)(s + j) << 6) + lane]; // sequential 256B rows
            int row  = (s + j < end) ? ((pk >> 16) & 63) : 64;
            atomicAdd(&sm[row * 65 + lane], f);              // ds_add_f32
        }
    }
    __syncthreads();

    int   kc  = cnt[cell0 + lane];
    float inv = kc ? 1.0f / (float)kc : 0.0f;      // empty voxel -> 0 (== 0/1e-5)
#pragma unroll
    for (int k = 0; k < 8; ++k) {
        int c = (wave << 3) + k;
        vox[(((size_t)(b * Cc + c)) << 15) + cell0loc + lane] = sm[lane * 65 + c] * inv;
    }
}

extern "C" void kernel_launch(void* const* d_in, const int* in_sizes, int n_in,
                              void* d_out, int out_size, void* d_ws, size_t ws_size,
                              hipStream_t stream)
{
    const float* features = (const float*)d_in[0];
    const float* coords   = (const float*)d_in[1];

    float* out      = (float*)d_out;
    float* vox      = out;
    float* norm_out = out + VOX_ELEMS;

    // ws layout: cnt | cursor | packed(+128) | bsums | slotbuf(idx->slot) | featS(+8 rows)
    char* ws = (char*)d_ws;
    int* cnt     = (int*)ws;  ws += (size_t)NCELL * 4;
    int* cursor  = (int*)ws;  ws += (size_t)NCELL * 4;
    int* packed  = (int*)ws;  ws += (size_t)(NSLOTS + 128) * 4;
    int* bsums   = (int*)ws;  ws += 2048 * 4;
    int* slotbuf = (int*)ws;  ws += (size_t)NSLOTS * 4;
    float* featS = (float*)ws;                      // (NSLOTS+8) * 64 floats

    hipMemsetAsync(cnt, 0, (size_t)NCELL * sizeof(int), stream);

    vox_coords_kernel<<<(Bb * Nn) / 256, 256, 0, stream>>>(coords, norm_out, slotbuf, cnt);
    scan1_kernel<<<NCELL / 256, 256, 0, stream>>>(cnt, cursor, bsums);
    scan2_kernel<<<1, 256, 0, stream>>>(bsums);
    scan3_kernel<<<NCELL / 256, 256, 0, stream>>>(cursor, bsums);
    bin_kernel<<<(Bb * Nn) / 256, 256, 0, stream>>>(slotbuf, cursor, packed);

    tscatter_kernel<<<Bb * 1024, 256, 0, stream>>>(features, slotbuf, featS);
    accum_kernel<<<Bb * 512, 512, 0, stream>>>(featS, cursor, cnt, packed, vox);
}

// Round 7
// 392.993 us; speedup vs baseline: 9.5298x; 1.7380x over previous
//
#include <hip/hip_runtime.h>

// features: (16, 64, 65536) f32, coords: (16, 3, 65536) f32, resolution = 32
constexpr int Rr = 32;
constexpr int R2 = Rr * Rr;          // 1024
constexpr int R3 = Rr * Rr * Rr;     // 32768
constexpr int Bb = 16;
constexpr int Cc = 64;
constexpr int Nn = 65536;
constexpr int VOX_ELEMS = Bb * Cc * R3;    // 33,554,432
constexpr int NCELL = Bb * R3;             // 524,288

// ---------------- K1: norm_coords + voxel idx + int counts ----------------
__global__ __launch_bounds__(256) void vox_coords_kernel(
    const float* __restrict__ coords,
    float* __restrict__ norm_out,
    int* __restrict__ idx_out,
    int* __restrict__ cnt)
{
    int t = blockIdx.x * 256 + threadIdx.x;        // t = b*N + i
    int b = t >> 16;
    int i = t & (Nn - 1);

    const float* cp = coords + (size_t)b * 3 * Nn + i;
    float x = cp[0];
    float y = cp[Nn];
    float z = cp[2 * Nn];

    float nx = fminf(fmaxf((x + 1.0f) * 16.0f, 0.0f), 31.0f);
    float ny = fminf(fmaxf((y + 1.0f) * 16.0f, 0.0f), 31.0f);
    float nz = fminf(fmaxf((z + 1.0f) * 16.0f, 0.0f), 31.0f);

    float* np_ = norm_out + (size_t)b * 3 * Nn + i;
    np_[0]      = nx;
    np_[Nn]     = ny;
    np_[2 * Nn] = nz;

    int idx = (int)rintf(nx) * R2 + (int)rintf(ny) * Rr + (int)rintf(nz);

    idx_out[t] = idx;
    atomicAdd(&cnt[(b << 15) + idx], 1);
}

// ---------------- K2: counts -> inverse (empty -> 0, giving exact 0 output) ----------------
__global__ __launch_bounds__(256) void inv_kernel(
    const int* __restrict__ cnt, float* __restrict__ inv)
{
    int t = blockIdx.x * 256 + threadIdx.x;        // total NCELL
    int c = cnt[t];
    inv[t] = c ? 1.0f / (float)c : 0.0f;
}

// ---------------- K3: coalesced read -> LDS transpose -> dense 256B atomic rows ----------------
__global__ __launch_bounds__(256) void tscatter_atomic_kernel(
    const float* __restrict__ feat,
    const int* __restrict__ idx_ws,
    const float* __restrict__ inv,
    float* __restrict__ voxT)
{
    __shared__ float lds[64 * 65];                 // [n][c], stride 65
    __shared__ int   cell_sm[64];
    __shared__ float inv_sm[64];
    int b    = blockIdx.x >> 10;
    int tile = blockIdx.x & 1023;
    int n0   = tile << 6;
    int t    = threadIdx.x;

    if (t < 64) {
        int cell = (b << 15) + idx_ws[(b << 16) + n0 + t];
        cell_sm[t] = cell;
        inv_sm[t]  = inv[cell];                    // random 4B in 2MB table -> L2 hit
    }

#pragma unroll
    for (int k = 0; k < 4; ++k) {
        int c  = (t >> 4) + (k << 4);
        int n4 = (t & 15) << 2;
        float4 v = *(const float4*)(feat + (((size_t)(b * Cc + c)) << 16) + n0 + n4);
        lds[(n4 + 0) * 65 + c] = v.x;
        lds[(n4 + 1) * 65 + c] = v.y;
        lds[(n4 + 2) * 65 + c] = v.z;
        lds[(n4 + 3) * 65 + c] = v.w;
    }
    __syncthreads();

    // each wave commits 16 point-rows; one instr = 64 consecutive 4B atomics (4 lines)
    int wave = t >> 6, lane = t & 63;
#pragma unroll
    for (int k = 0; k < 16; ++k) {
        int n = (wave << 4) + k;
        float f = lds[n * 65 + lane] * inv_sm[n];
        atomicAdd(&voxT[((size_t)cell_sm[n] << 6) + lane], f);   // fire-and-forget
    }
}

// ---------------- K4: transpose voxT (b,v,c) -> vox (b,c,v) ----------------
__global__ __launch_bounds__(256) void transpose_out_kernel(
    const float* __restrict__ voxT, float* __restrict__ vox)
{
    __shared__ float lds[64 * 65];                 // [v][c], stride 65
    int b    = blockIdx.x >> 9;
    int tile = blockIdx.x & 511;
    int v0   = tile << 6;
    int t    = threadIdx.x;

#pragma unroll
    for (int k = 0; k < 4; ++k) {
        int v  = (t >> 4) + (k << 4);              // 0..63
        int c4 = (t & 15) << 2;                    // 0..60
        float4 w = *(const float4*)(voxT + (((size_t)(b << 15) + v0 + v) << 6) + c4);
        lds[v * 65 + c4 + 0] = w.x;
        lds[v * 65 + c4 + 1] = w.y;
        lds[v * 65 + c4 + 2] = w.z;
        lds[v * 65 + c4 + 3] = w.w;
    }
    __syncthreads();

    int wave = t >> 6, lane = t & 63;
#pragma unroll
    for (int k = 0; k < 16; ++k) {
        int c = (wave << 4) + k;
        vox[(((size_t)(b * Cc + c)) << 15) + v0 + lane] = lds[lane * 65 + c];
    }
}

extern "C" void kernel_launch(void* const* d_in, const int* in_sizes, int n_in,
                              void* d_out, int out_size, void* d_ws, size_t ws_size,
                              hipStream_t stream)
{
    const float* features = (const float*)d_in[0];
    const float* coords   = (const float*)d_in[1];

    float* out      = (float*)d_out;
    float* vox      = out;
    float* norm_out = out + VOX_ELEMS;

    // ws layout: cnt (2MB) | inv (2MB) | idx (4MB) | voxT (134MB)
    char* ws = (char*)d_ws;
    int*   cnt    = (int*)ws;    ws += (size_t)NCELL * 4;
    float* inv    = (float*)ws;  ws += (size_t)NCELL * 4;
    int*   idx_ws = (int*)ws;    ws += (size_t)Bb * Nn * 4;
    float* voxT   = (float*)ws;  // NCELL * 64 floats = 134 MB

    hipMemsetAsync(cnt, 0, (size_t)NCELL * sizeof(int), stream);
    hipMemsetAsync(voxT, 0, (size_t)NCELL * 64 * sizeof(float), stream);

    vox_coords_kernel<<<(Bb * Nn) / 256, 256, 0, stream>>>(coords, norm_out, idx_ws, cnt);
    inv_kernel<<<NCELL / 256, 256, 0, stream>>>(cnt, inv);
    tscatter_atomic_kernel<<<Bb * 1024, 256, 0, stream>>>(features, idx_ws, inv, voxT);
    transpose_out_kernel<<<Bb * 512, 256, 0, stream>>>(voxT, vox);
}